// Round 15
// baseline (234.478 us; speedup 1.0000x reference)
//
#include <hip/hip_runtime.h>

typedef unsigned short u16;
typedef __bf16 bf16x4 __attribute__((ext_vector_type(4)));
typedef __bf16 bf16x8 __attribute__((ext_vector_type(8)));
typedef float f32x4 __attribute__((ext_vector_type(4)));

#define SEQ_LEN 4096
#define HID 1024
#define NHEAD 16
#define HDIM 64
#define MROWS 8192   // B*S
#define LOG2E 1.44269504088896f

__device__ __forceinline__ u16 f2bf(float f) {
  union { float f; unsigned u; } v; v.f = f;
  unsigned r = v.u + 0x7fffu + ((v.u >> 16) & 1u);
  return (u16)(r >> 16);
}

// raw hardware exp2 (v_exp_f32): avoids ocml libm path (no -ffast-math in harness)
__device__ __forceinline__ float fexp2(float x) {
  float r;
  asm("v_exp_f32 %0, %1" : "=v"(r) : "v"(x));
  return r;
}

// pack 8 f32 -> bf16x8 via hardware v_cvt_pk_bf16_f32
__device__ __forceinline__ bf16x8 pack8(f32x4 a, f32x4 b) {
  union { unsigned u[4]; bf16x8 v; } r;
  asm("v_cvt_pk_bf16_f32 %0, %1, %2" : "=v"(r.u[0]) : "v"(a[0]), "v"(a[1]));
  asm("v_cvt_pk_bf16_f32 %0, %1, %2" : "=v"(r.u[1]) : "v"(a[2]), "v"(a[3]));
  asm("v_cvt_pk_bf16_f32 %0, %1, %2" : "=v"(r.u[2]) : "v"(b[0]), "v"(b[1]));
  asm("v_cvt_pk_bf16_f32 %0, %1, %2" : "=v"(r.u[3]) : "v"(b[2]), "v"(b[3]));
  return r.v;
}

__device__ __forceinline__ void gload16(const void* g, void* lds) {
  __builtin_amdgcn_global_load_lds((const __attribute__((address_space(1))) void*)g,
                                   (__attribute__((address_space(3))) void*)lds, 16, 0, 0);
}

// ---------------- prep: x->bf16 + 4 weights->bf16 (mask check moved into gemm_qkv) ----------------

__global__ void prep_kernel(const float* __restrict__ x,
                            const float* __restrict__ w0, const float* __restrict__ w1,
                            const float* __restrict__ w2, const float* __restrict__ w3,
                            u16* __restrict__ xb, u16* __restrict__ wb) {
  const int NX = MROWS * HID / 4;        // 2,097,152
  const int NW = HID * HID / 4;          // 262,144 (= 2^18) per matrix
  const int TOT = NX + 4 * NW;
  int stride = gridDim.x * blockDim.x;
  for (int i = blockIdx.x * blockDim.x + threadIdx.x; i < TOT; i += stride) {
    if (i < NX) {
      float4 v = ((const float4*)x)[i];
      ((ushort4*)xb)[i] = make_ushort4(f2bf(v.x), f2bf(v.y), f2bf(v.z), f2bf(v.w));
    } else {
      int j = i - NX;
      int mat = j >> 18;
      int off = j & (NW - 1);
      const float* src = (mat == 0) ? w0 : (mat == 1) ? w1 : (mat == 2) ? w2 : w3;
      float4 v = ((const float4*)src)[off];
      ((ushort4*)(wb + (size_t)mat * HID * HID))[off] =
          make_ushort4(f2bf(v.x), f2bf(v.y), f2bf(v.z), f2bf(v.w));
    }
  }
}

// ---------------- GEMM core (y = A @ W^T), 128x128 tile, BK=64 ----------------

__device__ __forceinline__ void gemm_core(const u16* __restrict__ A, const u16* __restrict__ W,
                                          int m0, int n0, char* As, char* Bs, f32x4 acc[4][4]) {
  const int t = threadIdx.x, w = t >> 6, l = t & 63;
  const int lr = l & 15, lg = l >> 4;
  const int wr = (w >> 1) * 64, wc = (w & 1) * 64;
#pragma unroll
  for (int i = 0; i < 4; i++)
#pragma unroll
    for (int j = 0; j < 4; j++) acc[i][j] = (f32x4){0.f, 0.f, 0.f, 0.f};

  for (int k0 = 0; k0 < HID; k0 += 64) {
    __syncthreads();
#pragma unroll
    for (int j = 0; j < 4; j++) {
      int o = w * 4096 + j * 1024 + l * 16;
      int row = o >> 7, kb = (o >> 4) & 7, skb = kb ^ (row & 7);
      gload16(A + (size_t)(m0 + row) * HID + k0 + skb * 8, As + (w * 4096 + j * 1024));
      gload16(W + (size_t)(n0 + row) * HID + k0 + skb * 8, Bs + (w * 4096 + j * 1024));
    }
    __syncthreads();
#pragma unroll
    for (int ks = 0; ks < 2; ks++) {
      bf16x8 af[4], bf[4];
      int kb = ks * 4 + lg;
#pragma unroll
      for (int mt = 0; mt < 4; mt++) {
        int row = wr + mt * 16 + lr;
        af[mt] = *(const bf16x8*)(As + row * 128 + ((kb ^ (row & 7)) << 4));
      }
#pragma unroll
      for (int nt = 0; nt < 4; nt++) {
        int row = wc + nt * 16 + lr;
        bf[nt] = *(const bf16x8*)(Bs + row * 128 + ((kb ^ (row & 7)) << 4));
      }
#pragma unroll
      for (int mt = 0; mt < 4; mt++)
#pragma unroll
        for (int nt = 0; nt < 4; nt++)
          acc[mt][nt] = __builtin_amdgcn_mfma_f32_16x16x32_bf16(af[mt], bf[nt], acc[mt][nt], 0, 0, 0);
    }
  }
}

// QKV GEMM: gridDim = (64, 24). mat 0=Q (prescale log2e/8), 1=K, 2=V (transposed+permuted store)
// XCD-bijective block swizzle. Also scans the attention mask for nonzero (folded here:
// the GEMM is compute-bound, mask read rides on idle HBM bandwidth).
__global__ __launch_bounds__(256) void gemm_qkv_kernel(
    const u16* __restrict__ xb, const u16* __restrict__ wqb, const u16* __restrict__ wkb,
    const u16* __restrict__ wvb, const float* __restrict__ bq, const float* __restrict__ bk,
    const float* __restrict__ bv, const float* __restrict__ mask, int* __restrict__ flag,
    u16* __restrict__ Qb, u16* __restrict__ Kb, u16* __restrict__ VT) {
  __shared__ __align__(128) char lds[32768];
  int flat = blockIdx.y * 64 + blockIdx.x;   // HW XCD = flat & 7
  int xcd = flat & 7, j = flat >> 3;         // j in 0..191
  int bx = xcd * 8 + (j & 7);                // m-tile 0..63
  int by = j >> 3;                           // 0..23
  int m0 = bx * 128;
  int ng = by * 128;
  int mat = ng >> 10, n0 = ng & 1023;
  const u16* W = (mat == 0) ? wqb : (mat == 1) ? wkb : wvb;
  const float* bias = (mat == 0) ? bq : (mat == 1) ? bk : bv;

  // mask nonzero scan (hidden under the compute-bound GEMM)
  {
    const int NM = SEQ_LEN * SEQ_LEN / 4;
    const int nblk = 64 * 24;
    int per = (NM + nblk - 1) / nblk;
    int base = flat * per;
    int end = base + per < NM ? base + per : NM;
    bool nz = false;
    for (int i = base + threadIdx.x; i < end; i += 256) {
      float4 v = ((const float4*)mask)[i];
      nz |= (v.x != 0.f) | (v.y != 0.f) | (v.z != 0.f) | (v.w != 0.f);
    }
    if (__any(nz) && (threadIdx.x & 63) == 0) atomicOr(flag, 1);
  }

  f32x4 acc[4][4];
  gemm_core(xb, W, m0, n0, lds, lds + 16384, acc);

  const int t = threadIdx.x, w = t >> 6, l = t & 63;
  const int lr = l & 15, lg = l >> 4;
  if (mat < 2) {
    u16* dst = (mat == 0) ? Qb : Kb;
    float scale = (mat == 0) ? 0.125f * LOG2E : 1.0f;
#pragma unroll
    for (int mt = 0; mt < 4; mt++)
#pragma unroll
      for (int nt = 0; nt < 4; nt++) {
        int n = n0 + (w & 1) * 64 + nt * 16 + lr;
        float bn = bias[n];
#pragma unroll
        for (int i = 0; i < 4; i++) {
          int m = m0 + (w >> 1) * 64 + mt * 16 + lg * 4 + i;
          dst[(size_t)m * HID + n] = f2bf((acc[mt][nt][i] + bn) * scale);
        }
      }
  } else {
#pragma unroll
    for (int mt = 0; mt < 4; mt++)
#pragma unroll
      for (int nt = 0; nt < 4; nt++) {
        int m = m0 + (w >> 1) * 64 + mt * 16 + lg * 4;  // s base (4 consecutive, 4-aligned)
        int n = n0 + (w & 1) * 64 + nt * 16 + lr;       // d-global
        int b = m >> 12, s = m & 4095;
        int h = n >> 6, d = n & 63;
        // permute s within its 64-block so attn PV reads one 16B block per lane
        int t4 = (s >> 2) & 15;
        int t4p = ((t4 & 8)) | ((t4 & 3) << 1) | ((t4 >> 2) & 1);
        int sp = (s & ~63) | (t4p << 2);
        float bn = bias[n];
        ushort4 pk = make_ushort4(f2bf(acc[mt][nt][0] + bn), f2bf(acc[mt][nt][1] + bn),
                                  f2bf(acc[mt][nt][2] + bn), f2bf(acc[mt][nt][3] + bn));
        *(ushort4*)(VT + (((size_t)(b * NHEAD + h) * HDIM + d) * SEQ_LEN + sp)) = pk;
      }
  }
}

// out-proj GEMM: gridDim = (64, 8), fp32 output + bias. XCD-bijective swizzle as above.
__global__ __launch_bounds__(256) void gemm_out_kernel(
    const u16* __restrict__ Ob, const u16* __restrict__ wob, const float* __restrict__ bo,
    float* __restrict__ out) {
  __shared__ __align__(128) char lds[32768];
  int flat = blockIdx.y * 64 + blockIdx.x;
  int xcd = flat & 7, j = flat >> 3;         // j in 0..63
  int bx = xcd * 8 + (j & 7);
  int by = j >> 3;                           // 0..7
  int m0 = bx * 128, n0 = by * 128;
  f32x4 acc[4][4];
  gemm_core(Ob, wob, m0, n0, lds, lds + 16384, acc);
  const int t = threadIdx.x, w = t >> 6, l = t & 63;
  const int lr = l & 15, lg = l >> 4;
#pragma unroll
  for (int mt = 0; mt < 4; mt++)
#pragma unroll
    for (int nt = 0; nt < 4; nt++) {
      int n = n0 + (w & 1) * 64 + nt * 16 + lr;
      float bn = bo[n];
#pragma unroll
      for (int i = 0; i < 4; i++) {
        int m = m0 + (w >> 1) * 64 + mt * 16 + lg * 4 + i;
        out[(size_t)m * HID + n] = acc[mt][nt][i] + bn;
      }
    }
}

// ---------------- flash attention ----------------
// 512 blocks x 256 threads (4 waves). Each wave owns 64 q-rows (4 strips of 16);
// KVBLK=128: each LDS buffer holds TWO 64-kv sub-tiles (64 KB LDS total, still
// 2 blocks/CU) -> barrier count halves and prefetch is issued a full 4-phase
// (~1200 cyc) before its drain.
// Fast path (zero mask): P = 2^s directly. Masked path: online softmax w/ defer-max.
// XCD-locality swizzle; S^T = K.Q^T; P in registers; l via MFMA ones-trick;
// exp2 via raw v_exp_f32; P->bf16 via v_cvt_pk_bf16_f32.
__global__ __launch_bounds__(256, 2) void attn_kernel(
    const u16* __restrict__ Qb, const u16* __restrict__ Kb, const u16* __restrict__ VT,
    const float* __restrict__ mask, const int* __restrict__ flag, u16* __restrict__ Ob) {
  __shared__ __align__(128) char lds[65536];
  // buffer BI (32 KB each): K sub-tile T at BI*32768 + T*8192 (64 rows x 128B, swizzled)
  //                         V sub-tile T at BI*32768 + 16384 + T*8192
  const int flat = blockIdx.x;
  const int xcd = flat & 7;
  const int slot = flat >> 3;             // 0..63
  const int bh = xcd * 4 + (slot >> 4);   // 4 bh per XCD
  const int bx = slot & 15;
  const int q0 = bx * 256;
  const int b = bh >> 4, h = bh & 15;
  const int t = threadIdx.x, w = t >> 6, l = t & 63;
  const int lr = l & 15, lg = l >> 4;
  const bool useMask = (flag[0] != 0);
  int qrow[4];
#pragma unroll
  for (int s = 0; s < 4; s++) qrow[s] = q0 + w * 64 + s * 16 + lr;

  bf16x8 qf[4][2];
#pragma unroll
  for (int s = 0; s < 4; s++) {
    const u16* qp = Qb + (size_t)(b * SEQ_LEN + qrow[s]) * HID + h * HDIM;
#pragma unroll
    for (int ks = 0; ks < 2; ks++) qf[s][ks] = *(const bf16x8*)(qp + (ks * 4 + lg) * 8);
  }

  bf16x8 ones;
#pragma unroll
  for (int j = 0; j < 8; j++) ones[j] = (__bf16)1.0f;

  f32x4 oacc[4][4];
#pragma unroll
  for (int s = 0; s < 4; s++)
#pragma unroll
    for (int dt = 0; dt < 4; dt++) oacc[s][dt] = (f32x4){0.f, 0.f, 0.f, 0.f};
  f32x4 lacc[4];
#pragma unroll
  for (int s = 0; s < 4; s++) lacc[s] = (f32x4){0.f, 0.f, 0.f, 0.f};
  float m_r[4] = {-1e30f, -1e30f, -1e30f, -1e30f};

  // lane-constant swizzled LDS read offsets (shared by K and V reads: row = idx*16+lr)
  int off[2][4];
#pragma unroll
  for (int ks = 0; ks < 2; ks++) {
    int kb = ks * 4 + lg;
#pragma unroll
    for (int kt = 0; kt < 4; kt++) {
      int row = kt * 16 + lr;
      off[ks][kt] = row * 128 + ((kb ^ (row & 7)) << 4);
    }
  }

  // staging: per 128-kv buffer each thread issues 4 K + 4 V gloads (16B each)
  const int o0 = t * 16;                    // 0..4095
  const int o1 = o0 + 4096;
  const int r0 = t >> 3;                    // rows 0..31
  const int r1 = r0 + 32;                   // rows 32..63
  const int sk0 = (t & 7) ^ (r0 & 7);
  const int sk1 = (t & 7) ^ (r1 & 7);
  const u16* kg0 = Kb + (size_t)(b * SEQ_LEN) * HID + h * HDIM + (size_t)r0 * HID + sk0 * 8;
  const u16* kg1 = Kb + (size_t)(b * SEQ_LEN) * HID + h * HDIM + (size_t)r1 * HID + sk1 * 8;
  const u16* vg0 = VT + ((size_t)(b * NHEAD + h) * HDIM + r0) * SEQ_LEN + sk0 * 8;
  const u16* vg1 = VT + ((size_t)(b * NHEAD + h) * HDIM + r1) * SEQ_LEN + sk1 * 8;

#define STAGE(BI)                                                  \
  do {                                                             \
    gload16(kg0, lds + (BI) * 32768 + o0);                         \
    gload16(kg1, lds + (BI) * 32768 + o1);                         \
    gload16(kg0 + 64 * HID, lds + (BI) * 32768 + 8192 + o0);       \
    gload16(kg1 + 64 * HID, lds + (BI) * 32768 + 8192 + o1);       \
    gload16(vg0, lds + (BI) * 32768 + 16384 + o0);                 \
    gload16(vg1, lds + (BI) * 32768 + 16384 + o1);                 \
    gload16(vg0 + 64, lds + (BI) * 32768 + 24576 + o0);            \
    gload16(vg1 + 64, lds + (BI) * 32768 + 24576 + o1);            \
    kg0 += 128 * HID; kg1 += 128 * HID; vg0 += 128; vg1 += 128;    \
  } while (0)

// one 32-kv half of one 64-kv sub-tile: QK (4 strips) -> P -> PV.
#define HALF_HEAD(Ks, H)                                                                   \
    bf16x8 kf[2][2];                                                                       \
    _Pragma("unroll") for (int ks = 0; ks < 2; ks++)                                       \
    _Pragma("unroll") for (int ktl = 0; ktl < 2; ktl++)                                    \
        kf[ks][ktl] = *(const bf16x8*)((Ks) + off[ks][2 * (H) + ktl]);                     \
    f32x4 sf[4][2];                                                                        \
    _Pragma("unroll") for (int s = 0; s < 4; s++)                                          \
    _Pragma("unroll") for (int ktl = 0; ktl < 2; ktl++) sf[s][ktl] = (f32x4){0,0,0,0};     \
    __builtin_amdgcn_s_setprio(1);                                                         \
    _Pragma("unroll") for (int ks = 0; ks < 2; ks++)                                       \
    _Pragma("unroll") for (int s = 0; s < 4; s++)                                          \
    _Pragma("unroll") for (int ktl = 0; ktl < 2; ktl++)                                    \
        sf[s][ktl] = __builtin_amdgcn_mfma_f32_16x16x32_bf16(kf[ks][ktl], qf[s][ks],       \
                                                             sf[s][ktl], 0, 0, 0);        \
    __builtin_amdgcn_s_setprio(0);

#define HALF_TAIL(Vs, H)                                                                   \
    bf16x8 vf[4];                                                                          \
    _Pragma("unroll") for (int dt = 0; dt < 4; dt++)                                       \
        vf[dt] = *(const bf16x8*)((Vs) + off[H][dt]);                                      \
    bf16x8 pb[4];                                                                          \
    _Pragma("unroll") for (int s = 0; s < 4; s++)                                          \
        pb[s] = pack8(sf[s][0], sf[s][1]);                                                 \
    __builtin_amdgcn_s_setprio(1);                                                         \
    _Pragma("unroll") for (int s = 0; s < 4; s++) {                                        \
      _Pragma("unroll") for (int dt = 0; dt < 4; dt++)                                     \
          oacc[s][dt] =                                                                    \
              __builtin_amdgcn_mfma_f32_16x16x32_bf16(vf[dt], pb[s], oacc[s][dt], 0,0,0);  \
      lacc[s] = __builtin_amdgcn_mfma_f32_16x16x32_bf16(ones, pb[s], lacc[s], 0, 0, 0);    \
    }                                                                                      \
    __builtin_amdgcn_s_setprio(0);

#define HALF_FAST(BI, T, H)                                                                \
  do {                                                                                     \
    const char* Ks = lds + (BI) * 32768 + (T) * 8192;                                      \
    const char* Vs = lds + (BI) * 32768 + 16384 + (T) * 8192;                              \
    HALF_HEAD(Ks, H)                                                                       \
    _Pragma("unroll") for (int s = 0; s < 4; s++)                                          \
    _Pragma("unroll") for (int ktl = 0; ktl < 2; ktl++)                                    \
    _Pragma("unroll") for (int i = 0; i < 4; i++)                                          \
        sf[s][ktl][i] = fexp2(sf[s][ktl][i]);                                              \
    HALF_TAIL(Vs, H)                                                                       \
  } while (0)

#define HALF_SAFE(BI, T, H, KV0)                                                           \
  do {                                                                                     \
    const char* Ks = lds + (BI) * 32768 + (T) * 8192;                                      \
    const char* Vs = lds + (BI) * 32768 + 16384 + (T) * 8192;                              \
    HALF_HEAD(Ks, H)                                                                       \
    _Pragma("unroll") for (int s = 0; s < 4; s++)                                          \
    _Pragma("unroll") for (int ktl = 0; ktl < 2; ktl++)                                    \
    _Pragma("unroll") for (int i = 0; i < 4; i++)                                          \
        sf[s][ktl][i] += mask[(size_t)qrow[s] * SEQ_LEN + (KV0) + (T) * 64 +               \
                              (2 * (H) + ktl) * 16 + lg * 4 + i] * LOG2E;                  \
    float mx[4];                                                                           \
    _Pragma("unroll") for (int s = 0; s < 4; s++) {                                        \
      float m1 = fmaxf(fmaxf(sf[s][0][0], sf[s][0][1]), sf[s][0][2]);                      \
      m1 = fmaxf(fmaxf(m1, sf[s][0][3]), sf[s][1][0]);                                     \
      m1 = fmaxf(fmaxf(m1, sf[s][1][1]), sf[s][1][2]);                                     \
      m1 = fmaxf(m1, sf[s][1][3]);                                                         \
      m1 = fmaxf(m1, __shfl_xor(m1, 16));                                                  \
      mx[s] = fmaxf(m1, __shfl_xor(m1, 32));                                               \
    }                                                                                      \
    float dmax = fmaxf(fmaxf(mx[0] - m_r[0], mx[1] - m_r[1]),                              \
                       fmaxf(mx[2] - m_r[2], mx[3] - m_r[3]));                             \
    if (__any(dmax > 8.0f)) {                                                              \
      _Pragma("unroll") for (int s = 0; s < 4; s++) {                                      \
        float nm = fmaxf(m_r[s], mx[s]);                                                   \
        float scf = fexp2(m_r[s] - nm);                                                    \
        m_r[s] = nm;                                                                       \
        _Pragma("unroll") for (int dt = 0; dt < 4; dt++)                                   \
        _Pragma("unroll") for (int i = 0; i < 4; i++) oacc[s][dt][i] *= scf;               \
        lacc[s] *= scf;                                                                    \
      }                                                                                    \
    }                                                                                      \
    _Pragma("unroll") for (int s = 0; s < 4; s++)                                          \
    _Pragma("unroll") for (int ktl = 0; ktl < 2; ktl++)                                    \
    _Pragma("unroll") for (int i = 0; i < 4; i++)                                          \
        sf[s][ktl][i] = fexp2(sf[s][ktl][i] - m_r[s]);                                     \
    HALF_TAIL(Vs, H)                                                                       \
  } while (0)

  STAGE(0);
  __syncthreads();

  const int NT2 = SEQ_LEN / 128;   // 32 buffers of 128 kv; double-buffered -> 16 iters
  if (!useMask) {
    for (int t2 = 0; t2 < NT2 / 2; ++t2) {
      STAGE(1);
      HALF_FAST(0, 0, 0); HALF_FAST(0, 0, 1);
      HALF_FAST(0, 1, 0); HALF_FAST(0, 1, 1);
      __syncthreads();
      if (t2 != NT2 / 2 - 1) STAGE(0);
      HALF_FAST(1, 0, 0); HALF_FAST(1, 0, 1);
      HALF_FAST(1, 1, 0); HALF_FAST(1, 1, 1);
      __syncthreads();
    }
  } else {
    for (int t2 = 0; t2 < NT2 / 2; ++t2) {
      int kv0 = t2 * 256;
      STAGE(1);
      HALF_SAFE(0, 0, 0, kv0); HALF_SAFE(0, 0, 1, kv0);
      HALF_SAFE(0, 1, 0, kv0); HALF_SAFE(0, 1, 1, kv0);
      __syncthreads();
      if (t2 != NT2 / 2 - 1) STAGE(0);
      HALF_SAFE(1, 0, 0, kv0 + 128); HALF_SAFE(1, 0, 1, kv0 + 128);
      HALF_SAFE(1, 1, 0, kv0 + 128); HALF_SAFE(1, 1, 1, kv0 + 128);
      __syncthreads();
    }
  }
#undef STAGE
#undef HALF_HEAD
#undef HALF_TAIL
#undef HALF_FAST
#undef HALF_SAFE

  // epilogue
#pragma unroll
  for (int s = 0; s < 4; s++) {
    float inv = 1.0f / lacc[s][0];
    u16* orow = Ob + (size_t)(b * SEQ_LEN + qrow[s]) * HID + h * HDIM;
#pragma unroll
    for (int dt = 0; dt < 4; dt++) {
      ushort4 pk = make_ushort4(f2bf(oacc[s][dt][0] * inv), f2bf(oacc[s][dt][1] * inv),
                                f2bf(oacc[s][dt][2] * inv), f2bf(oacc[s][dt][3] * inv));
      *(ushort4*)(orow + dt * 16 + lg * 4) = pk;
    }
  }
}

// ---------------- launch ----------------

extern "C" void kernel_launch(void* const* d_in, const int* in_sizes, int n_in,
                              void* d_out, int out_size, void* d_ws, size_t ws_size,
                              hipStream_t stream) {
  const float* x    = (const float*)d_in[0];
  const float* mask = (const float*)d_in[1];
  const float* wq   = (const float*)d_in[2];
  const float* bq   = (const float*)d_in[3];
  const float* wk   = (const float*)d_in[4];
  const float* bk   = (const float*)d_in[5];
  const float* wv   = (const float*)d_in[6];
  const float* bv   = (const float*)d_in[7];
  const float* wo   = (const float*)d_in[8];
  const float* bo   = (const float*)d_in[9];

  char* ws = (char*)d_ws;
  u16* xb  = (u16*)(ws + 0);          // 16 MB (reused as Ob after QKV GEMM)
  u16* wqb = (u16*)(ws + 16777216);   // 2 MB each (wq,wk,wv,wo contiguous)
  u16* Qb  = (u16*)(ws + 25165824);   // 16 MB
  u16* Kb  = (u16*)(ws + 41943040);   // 16 MB
  u16* VT  = (u16*)(ws + 58720256);   // 16 MB
  int* flag = (int*)(ws + 75497472);
  u16* wkb = wqb + 1048576;
  u16* wvb = wqb + 2097152;
  u16* wob = wqb + 3145728;
  u16* Ob = xb;

  (void)hipMemsetAsync(flag, 0, 4, stream);
  prep_kernel<<<2048, 256, 0, stream>>>(x, wq, wk, wv, wo, xb, wqb);
  gemm_qkv_kernel<<<dim3(64, 24), 256, 0, stream>>>(xb, wqb, wkb, wvb, bq, bk, bv, mask, flag,
                                                    Qb, Kb, VT);
  attn_kernel<<<512, 256, 0, stream>>>(Qb, Kb, VT, mask, flag, Ob);
  gemm_out_kernel<<<dim3(64, 8), 256, 0, stream>>>(Ob, wob, bo, (float*)d_out);
}

// Round 17
// 230.733 us; speedup vs baseline: 1.0162x; 1.0162x over previous
//
#include <hip/hip_runtime.h>

typedef unsigned short u16;
typedef __bf16 bf16x4 __attribute__((ext_vector_type(4)));
typedef __bf16 bf16x8 __attribute__((ext_vector_type(8)));
typedef float f32x4 __attribute__((ext_vector_type(4)));

#define SEQ_LEN 4096
#define HID 1024
#define NHEAD 16
#define HDIM 64
#define MROWS 8192   // B*S
#define LOG2E 1.44269504088896f

__device__ __forceinline__ u16 f2bf(float f) {
  union { float f; unsigned u; } v; v.f = f;
  unsigned r = v.u + 0x7fffu + ((v.u >> 16) & 1u);
  return (u16)(r >> 16);
}

// raw hardware exp2 (v_exp_f32): avoids ocml libm path (no -ffast-math in harness)
__device__ __forceinline__ float fexp2(float x) {
  float r;
  asm("v_exp_f32 %0, %1" : "=v"(r) : "v"(x));
  return r;
}

// pack 8 f32 -> bf16x8 via hardware v_cvt_pk_bf16_f32
__device__ __forceinline__ bf16x8 pack8(f32x4 a, f32x4 b) {
  union { unsigned u[4]; bf16x8 v; } r;
  asm("v_cvt_pk_bf16_f32 %0, %1, %2" : "=v"(r.u[0]) : "v"(a[0]), "v"(a[1]));
  asm("v_cvt_pk_bf16_f32 %0, %1, %2" : "=v"(r.u[1]) : "v"(a[2]), "v"(a[3]));
  asm("v_cvt_pk_bf16_f32 %0, %1, %2" : "=v"(r.u[2]) : "v"(b[0]), "v"(b[1]));
  asm("v_cvt_pk_bf16_f32 %0, %1, %2" : "=v"(r.u[3]) : "v"(b[2]), "v"(b[3]));
  return r.v;
}

__device__ __forceinline__ void gload16(const void* g, void* lds) {
  __builtin_amdgcn_global_load_lds((const __attribute__((address_space(1))) void*)g,
                                   (__attribute__((address_space(3))) void*)lds, 16, 0, 0);
}

// ---------------- fused prep: x->bf16, 4 weights->bf16, mask nonzero check ----------------

__global__ void prep_kernel(const float* __restrict__ x,
                            const float* __restrict__ w0, const float* __restrict__ w1,
                            const float* __restrict__ w2, const float* __restrict__ w3,
                            const float* __restrict__ mask,
                            u16* __restrict__ xb, u16* __restrict__ wb, int* __restrict__ flag) {
  const int NX = MROWS * HID / 4;        // 2,097,152
  const int NW = HID * HID / 4;          // 262,144 (= 2^18) per matrix
  const int NM = SEQ_LEN * SEQ_LEN / 4;  // 4,194,304
  const int TOT = NX + 4 * NW + NM;
  int stride = gridDim.x * blockDim.x;
  bool nz = false;
  for (int i = blockIdx.x * blockDim.x + threadIdx.x; i < TOT; i += stride) {
    if (i < NX) {
      float4 v = ((const float4*)x)[i];
      ((ushort4*)xb)[i] = make_ushort4(f2bf(v.x), f2bf(v.y), f2bf(v.z), f2bf(v.w));
    } else if (i < NX + 4 * NW) {
      int j = i - NX;
      int mat = j >> 18;
      int off = j & (NW - 1);
      const float* src = (mat == 0) ? w0 : (mat == 1) ? w1 : (mat == 2) ? w2 : w3;
      float4 v = ((const float4*)src)[off];
      ((ushort4*)(wb + (size_t)mat * HID * HID))[off] =
          make_ushort4(f2bf(v.x), f2bf(v.y), f2bf(v.z), f2bf(v.w));
    } else {
      int j = i - NX - 4 * NW;
      float4 v = ((const float4*)mask)[j];
      nz |= (v.x != 0.f) | (v.y != 0.f) | (v.z != 0.f) | (v.w != 0.f);
    }
  }
  if (__any(nz) && (threadIdx.x & 63) == 0) atomicOr(flag, 1);
}

// ---------------- GEMM core (y = A @ W^T), 128x128 tile, BK=64 ----------------

__device__ __forceinline__ void gemm_core(const u16* __restrict__ A, const u16* __restrict__ W,
                                          int m0, int n0, char* As, char* Bs, f32x4 acc[4][4]) {
  const int t = threadIdx.x, w = t >> 6, l = t & 63;
  const int lr = l & 15, lg = l >> 4;
  const int wr = (w >> 1) * 64, wc = (w & 1) * 64;
#pragma unroll
  for (int i = 0; i < 4; i++)
#pragma unroll
    for (int j = 0; j < 4; j++) acc[i][j] = (f32x4){0.f, 0.f, 0.f, 0.f};

  for (int k0 = 0; k0 < HID; k0 += 64) {
    __syncthreads();
#pragma unroll
    for (int j = 0; j < 4; j++) {
      int o = w * 4096 + j * 1024 + l * 16;
      int row = o >> 7, kb = (o >> 4) & 7, skb = kb ^ (row & 7);
      gload16(A + (size_t)(m0 + row) * HID + k0 + skb * 8, As + (w * 4096 + j * 1024));
      gload16(W + (size_t)(n0 + row) * HID + k0 + skb * 8, Bs + (w * 4096 + j * 1024));
    }
    __syncthreads();
#pragma unroll
    for (int ks = 0; ks < 2; ks++) {
      bf16x8 af[4], bf[4];
      int kb = ks * 4 + lg;
#pragma unroll
      for (int mt = 0; mt < 4; mt++) {
        int row = wr + mt * 16 + lr;
        af[mt] = *(const bf16x8*)(As + row * 128 + ((kb ^ (row & 7)) << 4));
      }
#pragma unroll
      for (int nt = 0; nt < 4; nt++) {
        int row = wc + nt * 16 + lr;
        bf[nt] = *(const bf16x8*)(Bs + row * 128 + ((kb ^ (row & 7)) << 4));
      }
#pragma unroll
      for (int mt = 0; mt < 4; mt++)
#pragma unroll
        for (int nt = 0; nt < 4; nt++)
          acc[mt][nt] = __builtin_amdgcn_mfma_f32_16x16x32_bf16(af[mt], bf[nt], acc[mt][nt], 0, 0, 0);
    }
  }
}

// QKV GEMM: gridDim = (64, 24). mat 0=Q (prescale log2e/8), 1=K, 2=V (transposed+permuted store)
// XCD-bijective block swizzle: each XCD owns an 8-wide m-panel (2MB A, L2-resident).
__global__ __launch_bounds__(256) void gemm_qkv_kernel(
    const u16* __restrict__ xb, const u16* __restrict__ wqb, const u16* __restrict__ wkb,
    const u16* __restrict__ wvb, const float* __restrict__ bq, const float* __restrict__ bk,
    const float* __restrict__ bv, u16* __restrict__ Qb, u16* __restrict__ Kb, u16* __restrict__ VT) {
  __shared__ __align__(128) char lds[32768];
  int flat = blockIdx.y * 64 + blockIdx.x;   // HW XCD = flat & 7
  int xcd = flat & 7, j = flat >> 3;         // j in 0..191
  int bx = xcd * 8 + (j & 7);                // m-tile 0..63
  int by = j >> 3;                           // 0..23
  int m0 = bx * 128;
  int ng = by * 128;
  int mat = ng >> 10, n0 = ng & 1023;
  const u16* W = (mat == 0) ? wqb : (mat == 1) ? wkb : wvb;
  const float* bias = (mat == 0) ? bq : (mat == 1) ? bk : bv;
  f32x4 acc[4][4];
  gemm_core(xb, W, m0, n0, lds, lds + 16384, acc);

  const int t = threadIdx.x, w = t >> 6, l = t & 63;
  const int lr = l & 15, lg = l >> 4;
  if (mat < 2) {
    u16* dst = (mat == 0) ? Qb : Kb;
    float scale = (mat == 0) ? 0.125f * LOG2E : 1.0f;
#pragma unroll
    for (int mt = 0; mt < 4; mt++)
#pragma unroll
      for (int nt = 0; nt < 4; nt++) {
        int n = n0 + (w & 1) * 64 + nt * 16 + lr;
        float bn = bias[n];
#pragma unroll
        for (int i = 0; i < 4; i++) {
          int m = m0 + (w >> 1) * 64 + mt * 16 + lg * 4 + i;
          dst[(size_t)m * HID + n] = f2bf((acc[mt][nt][i] + bn) * scale);
        }
      }
  } else {
#pragma unroll
    for (int mt = 0; mt < 4; mt++)
#pragma unroll
      for (int nt = 0; nt < 4; nt++) {
        int m = m0 + (w >> 1) * 64 + mt * 16 + lg * 4;  // s base (4 consecutive, 4-aligned)
        int n = n0 + (w & 1) * 64 + nt * 16 + lr;       // d-global
        int b = m >> 12, s = m & 4095;
        int h = n >> 6, d = n & 63;
        // permute s within its 64-block so attn PV reads one 16B block per lane
        int t4 = (s >> 2) & 15;
        int t4p = ((t4 & 8)) | ((t4 & 3) << 1) | ((t4 >> 2) & 1);
        int sp = (s & ~63) | (t4p << 2);
        float bn = bias[n];
        ushort4 pk = make_ushort4(f2bf(acc[mt][nt][0] + bn), f2bf(acc[mt][nt][1] + bn),
                                  f2bf(acc[mt][nt][2] + bn), f2bf(acc[mt][nt][3] + bn));
        *(ushort4*)(VT + (((size_t)(b * NHEAD + h) * HDIM + d) * SEQ_LEN + sp)) = pk;
      }
  }
}

// out-proj GEMM: gridDim = (64, 8), fp32 output + bias. XCD-bijective swizzle as above.
__global__ __launch_bounds__(256) void gemm_out_kernel(
    const u16* __restrict__ Ob, const u16* __restrict__ wob, const float* __restrict__ bo,
    float* __restrict__ out) {
  __shared__ __align__(128) char lds[32768];
  int flat = blockIdx.y * 64 + blockIdx.x;
  int xcd = flat & 7, j = flat >> 3;         // j in 0..63
  int bx = xcd * 8 + (j & 7);
  int by = j >> 3;                           // 0..7
  int m0 = bx * 128, n0 = by * 128;
  f32x4 acc[4][4];
  gemm_core(Ob, wob, m0, n0, lds, lds + 16384, acc);
  const int t = threadIdx.x, w = t >> 6, l = t & 63;
  const int lr = l & 15, lg = l >> 4;
#pragma unroll
  for (int mt = 0; mt < 4; mt++)
#pragma unroll
    for (int nt = 0; nt < 4; nt++) {
      int n = n0 + (w & 1) * 64 + nt * 16 + lr;
      float bn = bo[n];
#pragma unroll
      for (int i = 0; i < 4; i++) {
        int m = m0 + (w >> 1) * 64 + mt * 16 + lg * 4 + i;
        out[(size_t)m * HID + n] = acc[mt][nt][i] + bn;
      }
    }
}

// ---------------- flash attention ----------------
// 512 blocks x 256 threads (4 waves). Each wave owns 64 q-rows (4 strips of 16);
// 64-kv tiles processed as two 32-kv halves (bounded transient registers).
// Fast path (zero mask): P = 2^s directly. Masked path: online softmax w/ defer-max.
// XCD-locality swizzle; S^T = K.Q^T; P in registers; l via MFMA ones-trick;
// double-buffered LDS; exp2 via raw v_exp_f32; P->bf16 via v_cvt_pk_bf16_f32.
__global__ __launch_bounds__(256, 2) void attn_kernel(
    const u16* __restrict__ Qb, const u16* __restrict__ Kb, const u16* __restrict__ VT,
    const float* __restrict__ mask, const int* __restrict__ flag, u16* __restrict__ Ob) {
  __shared__ __align__(128) char lds[32768];
  // K buf0 @0, K buf1 @8192, V buf0 @16384, V buf1 @24576 (64 rows x 128B, swizzled)
  const int flat = blockIdx.x;
  const int xcd = flat & 7;
  const int slot = flat >> 3;             // 0..63
  const int bh = xcd * 4 + (slot >> 4);   // 4 bh per XCD
  const int bx = slot & 15;
  const int q0 = bx * 256;
  const int b = bh >> 4, h = bh & 15;
  const int t = threadIdx.x, w = t >> 6, l = t & 63;
  const int lr = l & 15, lg = l >> 4;
  const bool useMask = (flag[0] != 0);
  int qrow[4];
#pragma unroll
  for (int s = 0; s < 4; s++) qrow[s] = q0 + w * 64 + s * 16 + lr;

  bf16x8 qf[4][2];
#pragma unroll
  for (int s = 0; s < 4; s++) {
    const u16* qp = Qb + (size_t)(b * SEQ_LEN + qrow[s]) * HID + h * HDIM;
#pragma unroll
    for (int ks = 0; ks < 2; ks++) qf[s][ks] = *(const bf16x8*)(qp + (ks * 4 + lg) * 8);
  }

  bf16x8 ones;
#pragma unroll
  for (int j = 0; j < 8; j++) ones[j] = (__bf16)1.0f;

  f32x4 oacc[4][4];
#pragma unroll
  for (int s = 0; s < 4; s++)
#pragma unroll
    for (int dt = 0; dt < 4; dt++) oacc[s][dt] = (f32x4){0.f, 0.f, 0.f, 0.f};
  f32x4 lacc[4];
#pragma unroll
  for (int s = 0; s < 4; s++) lacc[s] = (f32x4){0.f, 0.f, 0.f, 0.f};
  float m_r[4] = {-1e30f, -1e30f, -1e30f, -1e30f};

  // lane-constant swizzled LDS read offsets (shared by K and V reads: row = idx*16+lr)
  int off[2][4];
#pragma unroll
  for (int ks = 0; ks < 2; ks++) {
    int kb = ks * 4 + lg;
#pragma unroll
    for (int kt = 0; kt < 4; kt++) {
      int row = kt * 16 + lr;
      off[ks][kt] = row * 128 + ((kb ^ (row & 7)) << 4);
    }
  }

  // staging: 256 threads x 2x16B per tile per matrix
  const int o0 = t * 16;                    // 0..4095
  const int o1 = o0 + 4096;
  const int r0 = t >> 3;                    // rows 0..31
  const int r1 = r0 + 32;                   // rows 32..63
  const int sk0 = (t & 7) ^ (r0 & 7);
  const int sk1 = (t & 7) ^ (r1 & 7);
  const u16* kg0 = Kb + (size_t)(b * SEQ_LEN) * HID + h * HDIM + (size_t)r0 * HID + sk0 * 8;
  const u16* kg1 = Kb + (size_t)(b * SEQ_LEN) * HID + h * HDIM + (size_t)r1 * HID + sk1 * 8;
  const u16* vg0 = VT + ((size_t)(b * NHEAD + h) * HDIM + r0) * SEQ_LEN + sk0 * 8;
  const u16* vg1 = VT + ((size_t)(b * NHEAD + h) * HDIM + r1) * SEQ_LEN + sk1 * 8;

#define STAGE(BI)                                            \
  do {                                                       \
    gload16(kg0, lds + (BI) * 8192 + o0);                    \
    gload16(kg1, lds + (BI) * 8192 + o1);                    \
    gload16(vg0, lds + 16384 + (BI) * 8192 + o0);            \
    gload16(vg1, lds + 16384 + (BI) * 8192 + o1);            \
    kg0 += 64 * HID; kg1 += 64 * HID; vg0 += 64; vg1 += 64;  \
  } while (0)

// one 32-kv half: QK (4 strips) -> P -> PV. kf: kt = 2H+ktl; vf: block kb = H*4+lg.
#define HALF_HEAD(Ks, H)                                                                   \
    bf16x8 kf[2][2];                                                                       \
    _Pragma("unroll") for (int ks = 0; ks < 2; ks++)                                       \
    _Pragma("unroll") for (int ktl = 0; ktl < 2; ktl++)                                    \
        kf[ks][ktl] = *(const bf16x8*)((Ks) + off[ks][2 * (H) + ktl]);                     \
    f32x4 sf[4][2];                                                                        \
    _Pragma("unroll") for (int s = 0; s < 4; s++)                                          \
    _Pragma("unroll") for (int ktl = 0; ktl < 2; ktl++) sf[s][ktl] = (f32x4){0,0,0,0};     \
    __builtin_amdgcn_s_setprio(1);                                                         \
    _Pragma("unroll") for (int ks = 0; ks < 2; ks++)                                       \
    _Pragma("unroll") for (int s = 0; s < 4; s++)                                          \
    _Pragma("unroll") for (int ktl = 0; ktl < 2; ktl++)                                    \
        sf[s][ktl] = __builtin_amdgcn_mfma_f32_16x16x32_bf16(kf[ks][ktl], qf[s][ks],       \
                                                             sf[s][ktl], 0, 0, 0);        \
    __builtin_amdgcn_s_setprio(0);

#define HALF_TAIL(Vs, H)                                                                   \
    bf16x8 vf[4];                                                                          \
    _Pragma("unroll") for (int dt = 0; dt < 4; dt++)                                       \
        vf[dt] = *(const bf16x8*)((Vs) + off[H][dt]);                                      \
    bf16x8 pb[4];                                                                          \
    _Pragma("unroll") for (int s = 0; s < 4; s++)                                          \
        pb[s] = pack8(sf[s][0], sf[s][1]);                                                 \
    __builtin_amdgcn_s_setprio(1);                                                         \
    _Pragma("unroll") for (int s = 0; s < 4; s++) {                                        \
      _Pragma("unroll") for (int dt = 0; dt < 4; dt++)                                     \
          oacc[s][dt] =                                                                    \
              __builtin_amdgcn_mfma_f32_16x16x32_bf16(vf[dt], pb[s], oacc[s][dt], 0,0,0);  \
      lacc[s] = __builtin_amdgcn_mfma_f32_16x16x32_bf16(ones, pb[s], lacc[s], 0, 0, 0);    \
    }                                                                                      \
    __builtin_amdgcn_s_setprio(0);

#define HALF_FAST(BI, H)                                                                   \
  do {                                                                                     \
    const char* Ks = lds + (BI) * 8192;                                                    \
    const char* Vs = lds + 16384 + (BI) * 8192;                                            \
    HALF_HEAD(Ks, H)                                                                       \
    _Pragma("unroll") for (int s = 0; s < 4; s++)                                          \
    _Pragma("unroll") for (int ktl = 0; ktl < 2; ktl++)                                    \
    _Pragma("unroll") for (int i = 0; i < 4; i++)                                          \
        sf[s][ktl][i] = fexp2(sf[s][ktl][i]);                                              \
    HALF_TAIL(Vs, H)                                                                       \
  } while (0)

#define HALF_SAFE(BI, H, KV0)                                                              \
  do {                                                                                     \
    const char* Ks = lds + (BI) * 8192;                                                    \
    const char* Vs = lds + 16384 + (BI) * 8192;                                            \
    HALF_HEAD(Ks, H)                                                                       \
    _Pragma("unroll") for (int s = 0; s < 4; s++)                                          \
    _Pragma("unroll") for (int ktl = 0; ktl < 2; ktl++)                                    \
    _Pragma("unroll") for (int i = 0; i < 4; i++)                                          \
        sf[s][ktl][i] += mask[(size_t)qrow[s] * SEQ_LEN + (KV0) + (2 * (H) + ktl) * 16 +   \
                              lg * 4 + i] * LOG2E;                                         \
    float mx[4];                                                                           \
    _Pragma("unroll") for (int s = 0; s < 4; s++) {                                        \
      float m1 = fmaxf(fmaxf(sf[s][0][0], sf[s][0][1]), sf[s][0][2]);                      \
      m1 = fmaxf(fmaxf(m1, sf[s][0][3]), sf[s][1][0]);                                     \
      m1 = fmaxf(fmaxf(m1, sf[s][1][1]), sf[s][1][2]);                                     \
      m1 = fmaxf(m1, sf[s][1][3]);                                                         \
      m1 = fmaxf(m1, __shfl_xor(m1, 16));                                                  \
      mx[s] = fmaxf(m1, __shfl_xor(m1, 32));                                               \
    }                                                                                      \
    float dmax = fmaxf(fmaxf(mx[0] - m_r[0], mx[1] - m_r[1]),                              \
                       fmaxf(mx[2] - m_r[2], mx[3] - m_r[3]));                             \
    if (__any(dmax > 8.0f)) {                                                              \
      _Pragma("unroll") for (int s = 0; s < 4; s++) {                                      \
        float nm = fmaxf(m_r[s], mx[s]);                                                   \
        float scf = fexp2(m_r[s] - nm);                                                    \
        m_r[s] = nm;                                                                       \
        _Pragma("unroll") for (int dt = 0; dt < 4; dt++)                                   \
        _Pragma("unroll") for (int i = 0; i < 4; i++) oacc[s][dt][i] *= scf;               \
        lacc[s] *= scf;                                                                    \
      }                                                                                    \
    }                                                                                      \
    _Pragma("unroll") for (int s = 0; s < 4; s++)                                          \
    _Pragma("unroll") for (int ktl = 0; ktl < 2; ktl++)                                    \
    _Pragma("unroll") for (int i = 0; i < 4; i++)                                          \
        sf[s][ktl][i] = fexp2(sf[s][ktl][i] - m_r[s]);                                     \
    HALF_TAIL(Vs, H)                                                                       \
  } while (0)

  STAGE(0);
  __syncthreads();

  const int NT = SEQ_LEN / 64;
  if (!useMask) {
    for (int t2 = 0; t2 < NT / 2; ++t2) {
      STAGE(1);
      HALF_FAST(0, 0);
      HALF_FAST(0, 1);
      __syncthreads();
      if (t2 != NT / 2 - 1) STAGE(0);
      HALF_FAST(1, 0);
      HALF_FAST(1, 1);
      __syncthreads();
    }
  } else {
    for (int t2 = 0; t2 < NT / 2; ++t2) {
      STAGE(1);
      HALF_SAFE(0, 0, t2 * 128);
      HALF_SAFE(0, 1, t2 * 128);
      __syncthreads();
      if (t2 != NT / 2 - 1) STAGE(0);
      HALF_SAFE(1, 0, t2 * 128 + 64);
      HALF_SAFE(1, 1, t2 * 128 + 64);
      __syncthreads();
    }
  }
#undef STAGE
#undef HALF_HEAD
#undef HALF_TAIL
#undef HALF_FAST
#undef HALF_SAFE

  // epilogue
#pragma unroll
  for (int s = 0; s < 4; s++) {
    float inv = 1.0f / lacc[s][0];
    u16* orow = Ob + (size_t)(b * SEQ_LEN + qrow[s]) * HID + h * HDIM;
#pragma unroll
    for (int dt = 0; dt < 4; dt++) {
      ushort4 pk = make_ushort4(f2bf(oacc[s][dt][0] * inv), f2bf(oacc[s][dt][1] * inv),
                                f2bf(oacc[s][dt][2] * inv), f2bf(oacc[s][dt][3] * inv));
      *(ushort4*)(orow + dt * 16 + lg * 4) = pk;
    }
  }
}

// ---------------- launch ----------------

extern "C" void kernel_launch(void* const* d_in, const int* in_sizes, int n_in,
                              void* d_out, int out_size, void* d_ws, size_t ws_size,
                              hipStream_t stream) {
  const float* x    = (const float*)d_in[0];
  const float* mask = (const float*)d_in[1];
  const float* wq   = (const float*)d_in[2];
  const float* bq   = (const float*)d_in[3];
  const float* wk   = (const float*)d_in[4];
  const float* bk   = (const float*)d_in[5];
  const float* wv   = (const float*)d_in[6];
  const float* bv   = (const float*)d_in[7];
  const float* wo   = (const float*)d_in[8];
  const float* bo   = (const float*)d_in[9];

  char* ws = (char*)d_ws;
  u16* xb  = (u16*)(ws + 0);          // 16 MB (reused as Ob after QKV GEMM)
  u16* wqb = (u16*)(ws + 16777216);   // 2 MB each (wq,wk,wv,wo contiguous)
  u16* Qb  = (u16*)(ws + 25165824);   // 16 MB
  u16* Kb  = (u16*)(ws + 41943040);   // 16 MB
  u16* VT  = (u16*)(ws + 58720256);   // 16 MB
  int* flag = (int*)(ws + 75497472);
  u16* wkb = wqb + 1048576;
  u16* wvb = wqb + 2097152;
  u16* wob = wqb + 3145728;
  u16* Ob = xb;

  (void)hipMemsetAsync(flag, 0, 4, stream);
  prep_kernel<<<2048, 256, 0, stream>>>(x, wq, wk, wv, wo, mask, xb, wqb, flag);
  gemm_qkv_kernel<<<dim3(64, 24), 256, 0, stream>>>(xb, wqb, wkb, wvb, bq, bk, bv, Qb, Kb, VT);
  attn_kernel<<<512, 256, 0, stream>>>(Qb, Kb, VT, mask, flag, Ob);
  gemm_out_kernel<<<dim3(64, 8), 256, 0, stream>>>(Ob, wob, bo, (float*)d_out);
}